// Round 4
// baseline (84069.135 us; speedup 1.0000x reference)
//
#include <hip/hip_runtime.h>
#include <hip/hip_bf16.h>
#include <cstddef>

#define NN 32768
#define BM 64
#define BN 64
#define BK 32

typedef float f32x4 __attribute__((ext_vector_type(4)));
typedef short short8 __attribute__((ext_vector_type(8)));
typedef short short4v __attribute__((ext_vector_type(4)));

__device__ inline unsigned short f2bf(float f) {
    unsigned u = __builtin_bit_cast(unsigned, f);
    unsigned r = (u + 0x7FFFu + ((u >> 16) & 1u)) >> 16;
    return (unsigned short)r;
}
__device__ inline float sigmoid_f(float x) {
    float e = __expf(-x);
    return __builtin_amdgcn_rcpf(1.f + e);
}
__device__ inline float tanh_f(float x) {
    float e = __expf(-2.f * x);
    return 2.f * __builtin_amdgcn_rcpf(1.f + e) - 1.f;
}

// Gate-interleave permutation: permuted position p = w*64 + mt*16 + u'
// (w = wave, mt = gate index i/f/g/o, u' = unit-in-wave) maps to original
// gate row mt*128 + w*16 + u'.
__device__ inline int permrow(int p) {
    return ((p >> 4) & 3) * 128 + ((p >> 6) << 4) + (p & 15);
}

// Generic fp32 GEMM: C[M,N] = concat(A1[idx],A2[idx]) @ W[N,K].T + b1 (+ b2)
// permW: output column gc uses W row permrow(gc) and bias permrow(gc)
// (produces the gate-interleaved xg layout the scan kernel consumes).
__global__ __launch_bounds__(256) void gemm_cat(
    const float* __restrict__ A1, const int* __restrict__ idx1,
    const float* __restrict__ A2, const int* __restrict__ idx2, int istr,
    int K1, int K2,
    const float* __restrict__ W, const float* __restrict__ b1,
    const float* __restrict__ b2, int permW,
    float* __restrict__ C, int M, int N)
{
    const int K = K1 + K2;
    __shared__ __align__(16) float As[BK][BM + 4];  // [k][m]
    __shared__ __align__(16) float Ws[BK][BN + 4];  // [k][n]
    const int tid = threadIdx.x;
    const int m0 = blockIdx.x * BM;
    const int n0 = blockIdx.y * BN;
    const int tx = tid & 15;
    const int ty = tid >> 4;
    float acc[4][4] = {};

    for (int k0 = 0; k0 < K; k0 += BK) {
        #pragma unroll
        for (int p = 0; p < 2; ++p) {
            int q = tid + p * 256;
            int row = q >> 3;
            int kq = (q & 7) * 4;
            int gk = k0 + kq;
            int grow = m0 + row;
            const float* src;
            if (gk < K1) {
                int r = idx1 ? idx1[grow * istr] : grow;
                src = A1 + (size_t)r * K1 + gk;
            } else {
                int r = idx2 ? idx2[grow * istr] : grow;
                src = A2 + (size_t)r * K2 + (gk - K1);
            }
            float4 v = *(const float4*)src;
            As[kq + 0][row] = v.x; As[kq + 1][row] = v.y;
            As[kq + 2][row] = v.z; As[kq + 3][row] = v.w;
        }
        #pragma unroll
        for (int p = 0; p < 2; ++p) {
            int q = tid + p * 256;
            int row = q >> 3;
            int kq = (q & 7) * 4;
            int wrow = n0 + row;
            if (permW) wrow = permrow(wrow);
            const float* src = W + (size_t)wrow * K + (k0 + kq);
            float4 v = *(const float4*)src;
            Ws[kq + 0][row] = v.x; Ws[kq + 1][row] = v.y;
            Ws[kq + 2][row] = v.z; Ws[kq + 3][row] = v.w;
        }
        __syncthreads();
        #pragma unroll
        for (int kk = 0; kk < BK; ++kk) {
            float4 a = *(const float4*)&As[kk][ty * 4];
            float4 b = *(const float4*)&Ws[kk][tx * 4];
            float av[4] = {a.x, a.y, a.z, a.w};
            float bv[4] = {b.x, b.y, b.z, b.w};
            #pragma unroll
            for (int i = 0; i < 4; ++i)
                #pragma unroll
                for (int jj = 0; jj < 4; ++jj)
                    acc[i][jj] += av[i] * bv[jj];
        }
        __syncthreads();
    }
    #pragma unroll
    for (int i = 0; i < 4; ++i) {
        int gr = m0 + ty * 4 + i;
        #pragma unroll
        for (int jj = 0; jj < 4; ++jj) {
            int gc = n0 + tx * 4 + jj;
            int bi = permW ? permrow(gc) : gc;
            float bias = b1 ? b1[bi] : 0.f;
            if (b2) bias += b2[bi];
            C[(size_t)gr * N + gc] = acc[i][jj] + bias;
        }
    }
}

// MFMA LSTM scan, gate-interleaved. 1 block, 512 threads = 8 waves.
// Wave w's 64 MFMA rows = gates {i,f,g,o} (tile mt) x 16 units (w*16+u').
// A-frags hold original Whh rows mt*128 + w*16 + m, loaded once into regs.
// After MFMA each lane holds all 4 gates for units w*16+grp*4+{0..3}
// (D row = grp*4+reg, col = lane&15; B replicated so all cols identical)
// -> full c/h update in-register, no gate LDS round-trip.
// xg arrives PRE-PERMUTED from gemm_cat(permW=1): xg[t][w*64+mt*16+u'].
// hbuf double-buffered -> single barrier per step.
__global__ __launch_bounds__(512)
__attribute__((amdgpu_waves_per_eu(2, 2)))
void lstm_scan(const float* __restrict__ xg,    // [T, 512] permuted layout
               const float* __restrict__ Whh,   // [512, 128] fp32 original
               float* __restrict__ hs,          // [T, 128] fp32
               int T)
{
    __shared__ __align__(16) unsigned short hbuf[2][128];  // h in bf16
    const int tid  = threadIdx.x;
    const int w    = tid >> 6;
    const int lane = tid & 63;
    const int m    = lane & 15;   // A-row within 16-row tile (= D col)
    const int grp  = lane >> 4;   // k-group (A/B), row-group (D)

    // A fragments: tile mt row m = original Whh row mt*128 + w*16 + m
    short8 afrag[4][4];
    #pragma unroll
    for (int mt = 0; mt < 4; ++mt)
        #pragma unroll
        for (int kt = 0; kt < 4; ++kt) {
            const float* src = Whh + (size_t)(mt * 128 + w * 16 + m) * 128
                                   + kt * 32 + grp * 8;
            f32x4 v0 = *(const f32x4*)src;
            f32x4 v1 = *(const f32x4*)(src + 4);
            short8 s;
            s[0] = (short)f2bf(v0[0]); s[1] = (short)f2bf(v0[1]);
            s[2] = (short)f2bf(v0[2]); s[3] = (short)f2bf(v0[3]);
            s[4] = (short)f2bf(v1[0]); s[5] = (short)f2bf(v1[1]);
            s[6] = (short)f2bf(v1[2]); s[7] = (short)f2bf(v1[3]);
            afrag[mt][kt] = s;
        }

    if (tid < 128) { hbuf[0][tid] = 0; hbuf[1][tid] = 0; }

    // per-lane xg slices (every lane; 16 m-lanes hold identical copies)
    const int xoff = w * 64 + grp * 4;
    f32x4 xc[4], xn1[4], xn2[4];
    #pragma unroll
    for (int mt = 0; mt < 4; ++mt) {
        xc[mt]  = *(const f32x4*)(xg + xoff + mt * 16);
        xn1[mt] = *(const f32x4*)(xg + 512 + xoff + mt * 16);
        xn2[mt] = (f32x4){0.f, 0.f, 0.f, 0.f};
    }
    float c0 = 0.f, c1 = 0.f, c2 = 0.f, c3 = 0.f;
    __syncthreads();

    for (int t = 0; t < T; ++t) {
        const unsigned short* hb = hbuf[t & 1];
        short8 bfrag[4];
        #pragma unroll
        for (int kt = 0; kt < 4; ++kt)
            bfrag[kt] = *(const short8*)&hb[kt * 32 + grp * 8];

        f32x4 acc[4];
        #pragma unroll
        for (int mt = 0; mt < 4; ++mt) acc[mt] = (f32x4){0.f, 0.f, 0.f, 0.f};
        #pragma unroll
        for (int kt = 0; kt < 4; ++kt)       // kt outer: 4 interleaved chains
            #pragma unroll
            for (int mt = 0; mt < 4; ++mt)
                acc[mt] = __builtin_amdgcn_mfma_f32_16x16x32_bf16(
                    afrag[mt][kt], bfrag[kt], acc[mt], 0, 0, 0);

        // prefetch xg[t+2] while MFMA drains
        if (t + 2 < T) {
            const float* p = xg + (size_t)(t + 2) * 512 + xoff;
            #pragma unroll
            for (int mt = 0; mt < 4; ++mt) xn2[mt] = *(const f32x4*)(p + mt * 16);
        }

        // in-register state update: 4 units/lane, 4 independent chains
        float hv[4];
        {
            float iv0 = sigmoid_f(acc[0][0] + xc[0][0]);
            float fv0 = sigmoid_f(acc[1][0] + xc[1][0]);
            float gv0 = tanh_f   (acc[2][0] + xc[2][0]);
            float ov0 = sigmoid_f(acc[3][0] + xc[3][0]);
            float iv1 = sigmoid_f(acc[0][1] + xc[0][1]);
            float fv1 = sigmoid_f(acc[1][1] + xc[1][1]);
            float gv1 = tanh_f   (acc[2][1] + xc[2][1]);
            float ov1 = sigmoid_f(acc[3][1] + xc[3][1]);
            float iv2 = sigmoid_f(acc[0][2] + xc[0][2]);
            float fv2 = sigmoid_f(acc[1][2] + xc[1][2]);
            float gv2 = tanh_f   (acc[2][2] + xc[2][2]);
            float ov2 = sigmoid_f(acc[3][2] + xc[3][2]);
            float iv3 = sigmoid_f(acc[0][3] + xc[0][3]);
            float fv3 = sigmoid_f(acc[1][3] + xc[1][3]);
            float gv3 = tanh_f   (acc[2][3] + xc[2][3]);
            float ov3 = sigmoid_f(acc[3][3] + xc[3][3]);
            c0 = fv0 * c0 + iv0 * gv0;  hv[0] = ov0 * tanh_f(c0);
            c1 = fv1 * c1 + iv1 * gv1;  hv[1] = ov1 * tanh_f(c1);
            c2 = fv2 * c2 + iv2 * gv2;  hv[2] = ov2 * tanh_f(c2);
            c3 = fv3 * c3 + iv3 * gv3;  hv[3] = ov3 * tanh_f(c3);
        }

        if (m == 0) {   // one lane per (w,grp) writes units w*16+grp*4..+3
            short4v hp;
            hp[0] = (short)f2bf(hv[0]); hp[1] = (short)f2bf(hv[1]);
            hp[2] = (short)f2bf(hv[2]); hp[3] = (short)f2bf(hv[3]);
            *(short4v*)&hbuf[(t + 1) & 1][w * 16 + grp * 4] = hp;
            f32x4 ho = {hv[0], hv[1], hv[2], hv[3]};
            *(f32x4*)&hs[(size_t)t * 128 + w * 16 + grp * 4] = ho;
        }

        #pragma unroll
        for (int mt = 0; mt < 4; ++mt) { xc[mt] = xn1[mt]; xn1[mt] = xn2[mt]; }
        __syncthreads();   // hbuf[(t+1)&1] ready; prior reads drained
    }
}

extern "C" void kernel_launch(void* const* d_in, const int* in_sizes, int n_in,
                              void* d_out, int out_size, void* d_ws, size_t ws_size,
                              hipStream_t stream) {
    const float* inputs = (const float*)d_in[0];
    const int*   edges  = (const int*)d_in[1];     // [N,2] int32
    const float* in_W   = (const float*)d_in[2];   // [128,128]
    const float* in_b   = (const float*)d_in[3];   // [128]
    const float* out_W  = (const float*)d_in[4];   // [128,128]
    const float* out_b  = (const float*)d_in[5];   // [128]
    const float* edge_W = (const float*)d_in[6];   // [2,128,256]
    const float* edge_b = (const float*)d_in[7];   // [2,128]
    const float* Wih    = (const float*)d_in[8];   // [2,512,256]
    const float* Whh    = (const float*)d_in[9];   // [2,512,128]
    const float* bih    = (const float*)d_in[10];  // [2,512]
    const float* bhh    = (const float*)d_in[11];  // [2,512]
    float* out = (float*)d_out;

    float* ws = (float*)d_ws;
    float* nodesA = ws;                          // 32768*128
    float* nodesB = nodesA + (size_t)NN * 128;   // 32768*128
    float* edge_h = nodesB + (size_t)NN * 128;   // 32768*128
    float* xgbuf  = edge_h + (size_t)NN * 128;   // 32768*512

    dim3 blk(256);
    dim3 g128(NN / BM, 128 / BN);
    dim3 g512(NN / BM, 512 / BN);

    // nodes = inputs @ in_W.T + in_b
    gemm_cat<<<g128, blk, 0, stream>>>(inputs, nullptr, nullptr, nullptr, 1,
                                       128, 0, in_W, in_b, nullptr, 0,
                                       nodesA, NN, 128);

    const float* cur = nodesA;
    float* nxt = nodesB;
    for (int r = 0; r < 2; ++r) {
        // edge_h = concat(nodes[src], nodes[dst]) @ edge_W[r].T + edge_b[r]
        gemm_cat<<<g128, blk, 0, stream>>>(cur, edges + 0, cur, edges + 1, 2,
                                           128, 128,
                                           edge_W + (size_t)r * 128 * 256,
                                           edge_b + (size_t)r * 128, nullptr, 0,
                                           edge_h, NN, 128);
        // xg = concat(inputs, edge_h) @ Wih[r].T + bih[r] + bhh[r], PERMUTED
        gemm_cat<<<g512, blk, 0, stream>>>(inputs, nullptr, edge_h, nullptr, 1,
                                           128, 128,
                                           Wih + (size_t)r * 512 * 256,
                                           bih + (size_t)r * 512,
                                           bhh + (size_t)r * 512, 1,
                                           xgbuf, NN, 512);
        // sequential LSTM scan (MFMA, gate-interleaved)
        lstm_scan<<<1, 512, 0, stream>>>(xgbuf, Whh + (size_t)r * 512 * 128,
                                         nxt, NN);
        const float* tmp = cur;
        cur = nxt;
        nxt = (float*)tmp;
    }

    // out = nodes @ out_W.T + out_b
    gemm_cat<<<g128, blk, 0, stream>>>(cur, nullptr, nullptr, nullptr, 1,
                                       128, 0, out_W, out_b, nullptr, 0,
                                       out, NN, 128);
}

// Round 5
// 37769.312 us; speedup vs baseline: 2.2259x; 2.2259x over previous
//
#include <hip/hip_runtime.h>
#include <hip/hip_bf16.h>
#include <cstddef>

#define NN 32768
#define BM 64
#define BN 64
#define BK 32

typedef float f32x4 __attribute__((ext_vector_type(4)));
typedef short short8 __attribute__((ext_vector_type(8)));

__device__ inline unsigned short f2bf(float f) {
    unsigned u = __builtin_bit_cast(unsigned, f);
    unsigned r = (u + 0x7FFFu + ((u >> 16) & 1u)) >> 16;
    return (unsigned short)r;
}
__device__ inline float sigmoid_f(float x) {
    float e = __expf(-x);
    return __builtin_amdgcn_rcpf(1.f + e);
}
__device__ inline float tanh_f(float x) {
    float e = __expf(-2.f * x);
    return 2.f * __builtin_amdgcn_rcpf(1.f + e) - 1.f;
}

// Gate-interleave permutation: permuted position p = w*64 + nt*16 + u'
// (w = wave, nt = gate index i/f/g/o, u' = unit-in-wave) maps to original
// gate row nt*128 + w*16 + u'.
__device__ inline int permrow(int p) {
    return ((p >> 4) & 3) * 128 + ((p >> 6) << 4) + (p & 15);
}

// Generic fp32 GEMM: C[M,N] = concat(A1[idx],A2[idx]) @ W[N,K].T + b1 (+ b2)
// permW: output column gc uses W row permrow(gc) and bias permrow(gc).
__global__ __launch_bounds__(256) void gemm_cat(
    const float* __restrict__ A1, const int* __restrict__ idx1,
    const float* __restrict__ A2, const int* __restrict__ idx2, int istr,
    int K1, int K2,
    const float* __restrict__ W, const float* __restrict__ b1,
    const float* __restrict__ b2, int permW,
    float* __restrict__ C, int M, int N)
{
    const int K = K1 + K2;
    __shared__ __align__(16) float As[BK][BM + 4];  // [k][m]
    __shared__ __align__(16) float Ws[BK][BN + 4];  // [k][n]
    const int tid = threadIdx.x;
    const int m0 = blockIdx.x * BM;
    const int n0 = blockIdx.y * BN;
    const int tx = tid & 15;
    const int ty = tid >> 4;
    float acc[4][4] = {};

    for (int k0 = 0; k0 < K; k0 += BK) {
        #pragma unroll
        for (int p = 0; p < 2; ++p) {
            int q = tid + p * 256;
            int row = q >> 3;
            int kq = (q & 7) * 4;
            int gk = k0 + kq;
            int grow = m0 + row;
            const float* src;
            if (gk < K1) {
                int r = idx1 ? idx1[grow * istr] : grow;
                src = A1 + (size_t)r * K1 + gk;
            } else {
                int r = idx2 ? idx2[grow * istr] : grow;
                src = A2 + (size_t)r * K2 + (gk - K1);
            }
            float4 v = *(const float4*)src;
            As[kq + 0][row] = v.x; As[kq + 1][row] = v.y;
            As[kq + 2][row] = v.z; As[kq + 3][row] = v.w;
        }
        #pragma unroll
        for (int p = 0; p < 2; ++p) {
            int q = tid + p * 256;
            int row = q >> 3;
            int kq = (q & 7) * 4;
            int wrow = n0 + row;
            if (permW) wrow = permrow(wrow);
            const float* src = W + (size_t)wrow * K + (k0 + kq);
            float4 v = *(const float4*)src;
            Ws[kq + 0][row] = v.x; Ws[kq + 1][row] = v.y;
            Ws[kq + 2][row] = v.z; Ws[kq + 3][row] = v.w;
        }
        __syncthreads();
        #pragma unroll
        for (int kk = 0; kk < BK; ++kk) {
            float4 a = *(const float4*)&As[kk][ty * 4];
            float4 b = *(const float4*)&Ws[kk][tx * 4];
            float av[4] = {a.x, a.y, a.z, a.w};
            float bv[4] = {b.x, b.y, b.z, b.w};
            #pragma unroll
            for (int i = 0; i < 4; ++i)
                #pragma unroll
                for (int jj = 0; jj < 4; ++jj)
                    acc[i][jj] += av[i] * bv[jj];
        }
        __syncthreads();
    }
    #pragma unroll
    for (int i = 0; i < 4; ++i) {
        int gr = m0 + ty * 4 + i;
        #pragma unroll
        for (int jj = 0; jj < 4; ++jj) {
            int gc = n0 + tx * 4 + jj;
            int bi = permW ? permrow(gc) : gc;
            float bias = b1 ? b1[bi] : 0.f;
            if (b2) bias += b2[bi];
            C[(size_t)gr * N + gc] = acc[i][jj] + bias;
        }
    }
}

// MFMA LSTM scan, operand-swapped: D = A(h replicated) x B(Whh^T).
// 1 block, 512 threads = 8 waves; wave w owns units w*16..w*16+15.
// B tile nt = gate nt: B[k][col=u'] = Whh[nt*128 + w*16 + u'][k] -- the
// per-lane register load is identical to the old A-frag (row=lane&15,
// k=grp*8+j), only the operand position changes. A = h broadcast: every
// lane reads h[kt*32+grp*8..+7] from LDS (wave-uniform per grp -> bcast).
// Result: D col = lane&15 = unit, rows all identical => lane (grp,m) holds
// ALL 4 gates of unit w*16+m in acc[0..3][0] -- static indices, no
// cross-lane moves, 4 activations + 1 c/h chain per lane (round 4 had 16+4,
// VALUBusy 0.226 -> the 2x regression). xg folded into MFMA C operand.
__global__ __launch_bounds__(512)
__attribute__((amdgpu_waves_per_eu(2, 2)))
void lstm_scan(const float* __restrict__ xg,    // [T, 512] permuted layout
               const float* __restrict__ Whh,   // [512, 128] fp32 original
               float* __restrict__ hs,          // [T, 128] fp32
               int T)
{
    __shared__ __align__(16) unsigned short hbuf[2][128];  // h in bf16
    const int tid  = threadIdx.x;
    const int w    = tid >> 6;
    const int lane = tid & 63;
    const int m    = lane & 15;   // unit-in-wave (D column)
    const int grp  = lane >> 4;   // k-group for A/B frags

    // B fragments: gate tile nt, k-tile kt:
    // B[k = kt*32+grp*8+j][col = m] = Whh[nt*128 + w*16 + m][kt*32+grp*8+j]
    short8 wfrag[4][4];
    #pragma unroll
    for (int nt = 0; nt < 4; ++nt)
        #pragma unroll
        for (int kt = 0; kt < 4; ++kt) {
            const float* src = Whh + (size_t)(nt * 128 + w * 16 + m) * 128
                                   + kt * 32 + grp * 8;
            f32x4 v0 = *(const f32x4*)src;
            f32x4 v1 = *(const f32x4*)(src + 4);
            short8 s;
            s[0] = (short)f2bf(v0[0]); s[1] = (short)f2bf(v0[1]);
            s[2] = (short)f2bf(v0[2]); s[3] = (short)f2bf(v0[3]);
            s[4] = (short)f2bf(v1[0]); s[5] = (short)f2bf(v1[1]);
            s[6] = (short)f2bf(v1[2]); s[7] = (short)f2bf(v1[3]);
            wfrag[nt][kt] = s;
        }

    if (tid < 128) { hbuf[0][tid] = 0; hbuf[1][tid] = 0; }

    // per-lane xg: gate nt of unit w*16+m at permuted pos w*64 + nt*16 + m
    const int xoff = w * 64 + m;
    float xc[4], xn1[4], xn2[4];
    #pragma unroll
    for (int nt = 0; nt < 4; ++nt) {
        xc[nt]  = xg[xoff + nt * 16];
        xn1[nt] = xg[512 + xoff + nt * 16];
        xn2[nt] = 0.f;
    }
    float c = 0.f;
    __syncthreads();

    for (int t = 0; t < T; ++t) {
        // A fragments: h replicated across rows; lane reads h[kt*32+grp*8..+7]
        const unsigned short* hb = hbuf[t & 1];
        short8 hfrag[4];
        #pragma unroll
        for (int kt = 0; kt < 4; ++kt)
            hfrag[kt] = *(const short8*)&hb[kt * 32 + grp * 8];

        // C-init with xg (all 4 replica-rows get the same value)
        f32x4 acc[4];
        #pragma unroll
        for (int nt = 0; nt < 4; ++nt)
            acc[nt] = (f32x4){xc[nt], xc[nt], xc[nt], xc[nt]};

        #pragma unroll
        for (int kt = 0; kt < 4; ++kt)       // kt outer: 4 interleaved chains
            #pragma unroll
            for (int nt = 0; nt < 4; ++nt)
                acc[nt] = __builtin_amdgcn_mfma_f32_16x16x32_bf16(
                    hfrag[kt], wfrag[nt][kt], acc[nt], 0, 0, 0);

        // prefetch xg[t+2] while MFMA drains
        if (t + 2 < T) {
            const float* p = xg + (size_t)(t + 2) * 512 + xoff;
            #pragma unroll
            for (int nt = 0; nt < 4; ++nt) xn2[nt] = p[nt * 16];
        }

        // per-lane: all 4 gates of unit w*16+m, static indices
        float iv = sigmoid_f(acc[0][0]);
        float fv = sigmoid_f(acc[1][0]);
        float gv = tanh_f   (acc[2][0]);
        float ov = sigmoid_f(acc[3][0]);
        c = fv * c + iv * gv;
        float h = ov * tanh_f(c);

        if (grp == 0) {   // 16 lanes write this wave's 16 units
            hbuf[(t + 1) & 1][w * 16 + m] = f2bf(h);
            hs[(size_t)t * 128 + w * 16 + m] = h;
        }

        #pragma unroll
        for (int nt = 0; nt < 4; ++nt) { xc[nt] = xn1[nt]; xn1[nt] = xn2[nt]; }
        __syncthreads();   // hbuf[(t+1)&1] ready; prior reads drained
    }
}

extern "C" void kernel_launch(void* const* d_in, const int* in_sizes, int n_in,
                              void* d_out, int out_size, void* d_ws, size_t ws_size,
                              hipStream_t stream) {
    const float* inputs = (const float*)d_in[0];
    const int*   edges  = (const int*)d_in[1];     // [N,2] int32
    const float* in_W   = (const float*)d_in[2];   // [128,128]
    const float* in_b   = (const float*)d_in[3];   // [128]
    const float* out_W  = (const float*)d_in[4];   // [128,128]
    const float* out_b  = (const float*)d_in[5];   // [128]
    const float* edge_W = (const float*)d_in[6];   // [2,128,256]
    const float* edge_b = (const float*)d_in[7];   // [2,128]
    const float* Wih    = (const float*)d_in[8];   // [2,512,256]
    const float* Whh    = (const float*)d_in[9];   // [2,512,128]
    const float* bih    = (const float*)d_in[10];  // [2,512]
    const float* bhh    = (const float*)d_in[11];  // [2,512]
    float* out = (float*)d_out;

    float* ws = (float*)d_ws;
    float* nodesA = ws;                          // 32768*128
    float* nodesB = nodesA + (size_t)NN * 128;   // 32768*128
    float* edge_h = nodesB + (size_t)NN * 128;   // 32768*128
    float* xgbuf  = edge_h + (size_t)NN * 128;   // 32768*512

    dim3 blk(256);
    dim3 g128(NN / BM, 128 / BN);
    dim3 g512(NN / BM, 512 / BN);

    // nodes = inputs @ in_W.T + in_b
    gemm_cat<<<g128, blk, 0, stream>>>(inputs, nullptr, nullptr, nullptr, 1,
                                       128, 0, in_W, in_b, nullptr, 0,
                                       nodesA, NN, 128);

    const float* cur = nodesA;
    float* nxt = nodesB;
    for (int r = 0; r < 2; ++r) {
        // edge_h = concat(nodes[src], nodes[dst]) @ edge_W[r].T + edge_b[r]
        gemm_cat<<<g128, blk, 0, stream>>>(cur, edges + 0, cur, edges + 1, 2,
                                           128, 128,
                                           edge_W + (size_t)r * 128 * 256,
                                           edge_b + (size_t)r * 128, nullptr, 0,
                                           edge_h, NN, 128);
        // xg = concat(inputs, edge_h) @ Wih[r].T + bih[r] + bhh[r], PERMUTED
        gemm_cat<<<g512, blk, 0, stream>>>(inputs, nullptr, edge_h, nullptr, 1,
                                           128, 128,
                                           Wih + (size_t)r * 512 * 256,
                                           bih + (size_t)r * 512,
                                           bhh + (size_t)r * 512, 1,
                                           xgbuf, NN, 512);
        // sequential LSTM scan (MFMA, operand-swapped)
        lstm_scan<<<1, 512, 0, stream>>>(xgbuf, Whh + (size_t)r * 512 * 128,
                                         nxt, NN);
        const float* tmp = cur;
        cur = nxt;
        nxt = (float*)tmp;
    }

    // out = nodes @ out_W.T + out_b
    gemm_cat<<<g128, blk, 0, stream>>>(cur, nullptr, nullptr, nullptr, 1,
                                       128, 0, out_W, out_b, nullptr, 0,
                                       out, NN, 128);
}

// Round 6
// 30190.244 us; speedup vs baseline: 2.7846x; 1.2510x over previous
//
#include <hip/hip_runtime.h>
#include <hip/hip_bf16.h>
#include <cstddef>

#define NN 32768
#define BM 64
#define BN 64
#define BK 32

typedef float f32x4 __attribute__((ext_vector_type(4)));
typedef short short8 __attribute__((ext_vector_type(8)));

__device__ inline unsigned short f2bf(float f) {
    unsigned u = __builtin_bit_cast(unsigned, f);
    unsigned r = (u + 0x7FFFu + ((u >> 16) & 1u)) >> 16;
    return (unsigned short)r;
}
__device__ inline float sigmoid_f(float x) {
    float e = __expf(-x);
    return __builtin_amdgcn_rcpf(1.f + e);
}
__device__ inline float tanh_f(float x) {
    float e = __expf(-2.f * x);
    return 2.f * __builtin_amdgcn_rcpf(1.f + e) - 1.f;
}

// Gate-interleave permutation: permuted position p = w*64 + nt*16 + u'
// (w = wave, nt = gate index i/f/g/o, u' = unit-in-wave) maps to original
// gate row nt*128 + w*16 + u'.
__device__ inline int permrow(int p) {
    return ((p >> 4) & 3) * 128 + ((p >> 6) << 4) + (p & 15);
}

// Generic fp32 GEMM: C[M,N] = concat(A1[idx],A2[idx]) @ W[N,K].T + b1 (+ b2)
// permW: output column gc uses W row permrow(gc) and bias permrow(gc).
__global__ __launch_bounds__(256) void gemm_cat(
    const float* __restrict__ A1, const int* __restrict__ idx1,
    const float* __restrict__ A2, const int* __restrict__ idx2, int istr,
    int K1, int K2,
    const float* __restrict__ W, const float* __restrict__ b1,
    const float* __restrict__ b2, int permW,
    float* __restrict__ C, int M, int N)
{
    const int K = K1 + K2;
    __shared__ __align__(16) float As[BK][BM + 4];  // [k][m]
    __shared__ __align__(16) float Ws[BK][BN + 4];  // [k][n]
    const int tid = threadIdx.x;
    const int m0 = blockIdx.x * BM;
    const int n0 = blockIdx.y * BN;
    const int tx = tid & 15;
    const int ty = tid >> 4;
    float acc[4][4] = {};

    for (int k0 = 0; k0 < K; k0 += BK) {
        #pragma unroll
        for (int p = 0; p < 2; ++p) {
            int q = tid + p * 256;
            int row = q >> 3;
            int kq = (q & 7) * 4;
            int gk = k0 + kq;
            int grow = m0 + row;
            const float* src;
            if (gk < K1) {
                int r = idx1 ? idx1[grow * istr] : grow;
                src = A1 + (size_t)r * K1 + gk;
            } else {
                int r = idx2 ? idx2[grow * istr] : grow;
                src = A2 + (size_t)r * K2 + (gk - K1);
            }
            float4 v = *(const float4*)src;
            As[kq + 0][row] = v.x; As[kq + 1][row] = v.y;
            As[kq + 2][row] = v.z; As[kq + 3][row] = v.w;
        }
        #pragma unroll
        for (int p = 0; p < 2; ++p) {
            int q = tid + p * 256;
            int row = q >> 3;
            int kq = (q & 7) * 4;
            int wrow = n0 + row;
            if (permW) wrow = permrow(wrow);
            const float* src = W + (size_t)wrow * K + (k0 + kq);
            float4 v = *(const float4*)src;
            Ws[kq + 0][row] = v.x; Ws[kq + 1][row] = v.y;
            Ws[kq + 2][row] = v.z; Ws[kq + 3][row] = v.w;
        }
        __syncthreads();
        #pragma unroll
        for (int kk = 0; kk < BK; ++kk) {
            float4 a = *(const float4*)&As[kk][ty * 4];
            float4 b = *(const float4*)&Ws[kk][tx * 4];
            float av[4] = {a.x, a.y, a.z, a.w};
            float bv[4] = {b.x, b.y, b.z, b.w};
            #pragma unroll
            for (int i = 0; i < 4; ++i)
                #pragma unroll
                for (int jj = 0; jj < 4; ++jj)
                    acc[i][jj] += av[i] * bv[jj];
        }
        __syncthreads();
    }
    #pragma unroll
    for (int i = 0; i < 4; ++i) {
        int gr = m0 + ty * 4 + i;
        #pragma unroll
        for (int jj = 0; jj < 4; ++jj) {
            int gc = n0 + tx * 4 + jj;
            int bi = permW ? permrow(gc) : gc;
            float bias = b1 ? b1[bi] : 0.f;
            if (b2) bias += b2[bi];
            C[(size_t)gr * N + gc] = acc[i][jj] + bias;
        }
    }
}

// MFMA LSTM scan, operand-swapped (round 5 structure), VALU-trimmed:
//  - acc persistent across steps; only element 0 (D row grp*4 -- the one
//    element we read) is re-initialized from xg each step (4 movs vs 16).
//    Elements 1..3 accumulate bounded garbage (random walk of gate sums,
//    << fp32 range; finite inputs -> no NaN/Inf; never read).
//  - t-loop unrolled by 2: static hbuf ping-pong, named xcA/xcB register
//    sets (no shift movs), carried pointers for xg prefetch and hs store.
// Round-5 counters: VALUBusy/CU 46% > MfmaUtil/CU 37% -> VALU issue is the
// binding resource; this round cuts ~35 VALU instr/step/wave.
__global__ __launch_bounds__(512)
__attribute__((amdgpu_waves_per_eu(2, 2)))
void lstm_scan(const float* __restrict__ xg,    // [T, 512] permuted layout
               const float* __restrict__ Whh,   // [512, 128] fp32 original
               float* __restrict__ hs,          // [T, 128] fp32
               int T)
{
    __shared__ __align__(16) unsigned short hbuf[2][128];  // h in bf16
    const int tid  = threadIdx.x;
    const int w    = tid >> 6;
    const int lane = tid & 63;
    const int m    = lane & 15;   // unit-in-wave (D column)
    const int grp  = lane >> 4;   // k-group for A/B frags

    // B fragments: gate tile nt, k-tile kt:
    // B[k = kt*32+grp*8+j][col = m] = Whh[nt*128 + w*16 + m][kt*32+grp*8+j]
    short8 wfrag[4][4];
    #pragma unroll
    for (int nt = 0; nt < 4; ++nt)
        #pragma unroll
        for (int kt = 0; kt < 4; ++kt) {
            const float* src = Whh + (size_t)(nt * 128 + w * 16 + m) * 128
                                   + kt * 32 + grp * 8;
            f32x4 v0 = *(const f32x4*)src;
            f32x4 v1 = *(const f32x4*)(src + 4);
            short8 s;
            s[0] = (short)f2bf(v0[0]); s[1] = (short)f2bf(v0[1]);
            s[2] = (short)f2bf(v0[2]); s[3] = (short)f2bf(v0[3]);
            s[4] = (short)f2bf(v1[0]); s[5] = (short)f2bf(v1[1]);
            s[6] = (short)f2bf(v1[2]); s[7] = (short)f2bf(v1[3]);
            wfrag[nt][kt] = s;
        }

    if (tid < 128) { hbuf[0][tid] = 0; hbuf[1][tid] = 0; }

    // xg: gate nt of unit w*16+m at permuted pos w*64 + nt*16 + m
    const int xoff = w * 64 + m;
    float xcA[4], xcB[4];
    #pragma unroll
    for (int nt = 0; nt < 4; ++nt) {
        xcA[nt] = xg[xoff + nt * 16];          // step 0
        xcB[nt] = xg[512 + xoff + nt * 16];    // step 1
    }
    const float* xpre = xg + 2 * 512 + xoff;   // prefetch base (step t+2)
    float* hsp = hs + w * 16 + m;              // store base (grp==0 lanes)
    float c = 0.f;
    f32x4 acc[4];
    #pragma unroll
    for (int nt = 0; nt < 4; ++nt) acc[nt] = (f32x4){0.f, 0.f, 0.f, 0.f};
    __syncthreads();

    for (int t = 0; t < T; t += 2) {
        // ================ even sub-step (t): read hbuf[0] -> write hbuf[1]
        {
            short8 hfrag[4];
            #pragma unroll
            for (int kt = 0; kt < 4; ++kt)
                hfrag[kt] = *(const short8*)&hbuf[0][kt * 32 + grp * 8];

            #pragma unroll
            for (int nt = 0; nt < 4; ++nt) acc[nt][0] = xcA[nt];

            // prefetch xg[t+2] -> xcA (consumed above; latency hidden under
            // the MFMA + activation phases)
            if (t + 2 < T) {
                #pragma unroll
                for (int nt = 0; nt < 4; ++nt) xcA[nt] = xpre[nt * 16];
            }

            #pragma unroll
            for (int kt = 0; kt < 4; ++kt)   // kt outer: 4 interleaved chains
                #pragma unroll
                for (int nt = 0; nt < 4; ++nt)
                    acc[nt] = __builtin_amdgcn_mfma_f32_16x16x32_bf16(
                        hfrag[kt], wfrag[nt][kt], acc[nt], 0, 0, 0);

            float iv = sigmoid_f(acc[0][0]);
            float fv = sigmoid_f(acc[1][0]);
            float gv = tanh_f   (acc[2][0]);
            float ov = sigmoid_f(acc[3][0]);
            c = fv * c + iv * gv;
            float h = ov * tanh_f(c);

            if (grp == 0) {
                hbuf[1][w * 16 + m] = f2bf(h);
                hsp[0] = h;
            }
            __syncthreads();
        }
        // ================ odd sub-step (t+1): read hbuf[1] -> write hbuf[0]
        {
            short8 hfrag[4];
            #pragma unroll
            for (int kt = 0; kt < 4; ++kt)
                hfrag[kt] = *(const short8*)&hbuf[1][kt * 32 + grp * 8];

            #pragma unroll
            for (int nt = 0; nt < 4; ++nt) acc[nt][0] = xcB[nt];

            if (t + 3 < T) {
                #pragma unroll
                for (int nt = 0; nt < 4; ++nt) xcB[nt] = xpre[512 + nt * 16];
            }

            #pragma unroll
            for (int kt = 0; kt < 4; ++kt)
                #pragma unroll
                for (int nt = 0; nt < 4; ++nt)
                    acc[nt] = __builtin_amdgcn_mfma_f32_16x16x32_bf16(
                        hfrag[kt], wfrag[nt][kt], acc[nt], 0, 0, 0);

            float iv = sigmoid_f(acc[0][0]);
            float fv = sigmoid_f(acc[1][0]);
            float gv = tanh_f   (acc[2][0]);
            float ov = sigmoid_f(acc[3][0]);
            c = fv * c + iv * gv;
            float h = ov * tanh_f(c);

            if (grp == 0) {
                hbuf[0][w * 16 + m] = f2bf(h);
                hsp[128] = h;
            }
            __syncthreads();
        }
        xpre += 1024;
        hsp  += 256;
    }
}

extern "C" void kernel_launch(void* const* d_in, const int* in_sizes, int n_in,
                              void* d_out, int out_size, void* d_ws, size_t ws_size,
                              hipStream_t stream) {
    const float* inputs = (const float*)d_in[0];
    const int*   edges  = (const int*)d_in[1];     // [N,2] int32
    const float* in_W   = (const float*)d_in[2];   // [128,128]
    const float* in_b   = (const float*)d_in[3];   // [128]
    const float* out_W  = (const float*)d_in[4];   // [128,128]
    const float* out_b  = (const float*)d_in[5];   // [128]
    const float* edge_W = (const float*)d_in[6];   // [2,128,256]
    const float* edge_b = (const float*)d_in[7];   // [2,128]
    const float* Wih    = (const float*)d_in[8];   // [2,512,256]
    const float* Whh    = (const float*)d_in[9];   // [2,512,128]
    const float* bih    = (const float*)d_in[10];  // [2,512]
    const float* bhh    = (const float*)d_in[11];  // [2,512]
    float* out = (float*)d_out;

    float* ws = (float*)d_ws;
    float* nodesA = ws;                          // 32768*128
    float* nodesB = nodesA + (size_t)NN * 128;   // 32768*128
    float* edge_h = nodesB + (size_t)NN * 128;   // 32768*128
    float* xgbuf  = edge_h + (size_t)NN * 128;   // 32768*512

    dim3 blk(256);
    dim3 g128(NN / BM, 128 / BN);
    dim3 g512(NN / BM, 512 / BN);

    // nodes = inputs @ in_W.T + in_b
    gemm_cat<<<g128, blk, 0, stream>>>(inputs, nullptr, nullptr, nullptr, 1,
                                       128, 0, in_W, in_b, nullptr, 0,
                                       nodesA, NN, 128);

    const float* cur = nodesA;
    float* nxt = nodesB;
    for (int r = 0; r < 2; ++r) {
        // edge_h = concat(nodes[src], nodes[dst]) @ edge_W[r].T + edge_b[r]
        gemm_cat<<<g128, blk, 0, stream>>>(cur, edges + 0, cur, edges + 1, 2,
                                           128, 128,
                                           edge_W + (size_t)r * 128 * 256,
                                           edge_b + (size_t)r * 128, nullptr, 0,
                                           edge_h, NN, 128);
        // xg = concat(inputs, edge_h) @ Wih[r].T + bih[r] + bhh[r], PERMUTED
        gemm_cat<<<g512, blk, 0, stream>>>(inputs, nullptr, edge_h, nullptr, 1,
                                           128, 128,
                                           Wih + (size_t)r * 512 * 256,
                                           bih + (size_t)r * 512,
                                           bhh + (size_t)r * 512, 1,
                                           xgbuf, NN, 512);
        // sequential LSTM scan (MFMA, operand-swapped, VALU-trimmed)
        lstm_scan<<<1, 512, 0, stream>>>(xgbuf, Whh + (size_t)r * 512 * 128,
                                         nxt, NN);
        const float* tmp = cur;
        cur = nxt;
        nxt = (float*)tmp;
    }

    // out = nodes @ out_W.T + out_b
    gemm_cat<<<g128, blk, 0, stream>>>(cur, nullptr, nullptr, nullptr, 1,
                                       128, 0, out_W, out_b, nullptr, 0,
                                       out, NN, 128);
}